// Round 10
// baseline (435.738 us; speedup 1.0000x reference)
//
#include <hip/hip_runtime.h>

// ---------------------------------------------------------------------------
// GCN 2-layer fused pipeline for MI355X (gfx950)
//   h1 = relu(Dinv (A+I) Dinv (x@W1) + b1)
//   out = 0.5*(h1@Wc + bc) + 0.5*((alpha*h2 + (1-alpha)*h1)@Wf + bf)
//   h2 = relu(Dinv (A+I) Dinv (h1@W2) + b2)
// R2: binned counting-sort CSR. R3: fused dinv into colv. R5/R6: multi-edge
// wide gathers. R8: 1-dword colv, packed f32x2 agg math (aggs now at ~87%
// of their gather latency-MLP envelope -> frozen). R9: barrier-free
// register-pipelined GEMM (fp32 path was VGPR-fat: ~180 -> 2 waves/SIMD).
// R10: structural round. (a) x converted to bf16 in the prep dispatch so
// gemm1 uses the lean bf16 pipe (half A-bytes, ~3 waves/SIMD); (b) role-split
// co-launches: D1=[convert|wt1|wt2|bincount], D3=[stage|gemm1] (stage hides
// inside latency-bound gemm1); (c) 10 -> 8 dispatches.
// ---------------------------------------------------------------------------

#define HID 128
#define SHIFT 9
#define RANGE 512           // nodes per bin = 1<<SHIFT
#define MAXB 256            // max bins (N <= 131072)
#define TILE 4096           // edges per stage block

typedef __bf16 bf16x8 __attribute__((ext_vector_type(8)));
typedef float  f32x4  __attribute__((ext_vector_type(4)));
typedef float  f32x2  __attribute__((ext_vector_type(2)));

__device__ __forceinline__ unsigned short f2bf(float x) {
    unsigned int b = __float_as_uint(x);
    b += 0x7fffu + ((b >> 16) & 1u);     // round-to-nearest-even
    return (unsigned short)(b >> 16);
}
__device__ __forceinline__ float bflo(unsigned int u) { return __uint_as_float(u << 16); }
__device__ __forceinline__ float bfhi(unsigned int u) { return __uint_as_float(u & 0xffff0000u); }
__device__ __forceinline__ unsigned packbf(float a, float b) {
    return (unsigned)f2bf(a) | ((unsigned)f2bf(b) << 16);
}

// --------------------------- CSR build bodies ------------------------------

__device__ void bincount_body(int blk, const int* __restrict__ dst,
                              int* __restrict__ bin_counts, int E, int NB) {
    __shared__ int h[MAXB];
    for (int i = threadIdx.x; i < NB; i += 256) h[i] = 0;
    __syncthreads();
    const int base = blk * TILE;
#pragma unroll
    for (int j = 0; j < TILE; j += 256) {
        int e = base + j + threadIdx.x;
        if (e < E) atomicAdd(&h[((unsigned)dst[e]) >> SHIFT], 1);
    }
    __syncthreads();
    for (int i = threadIdx.x; i < NB; i += 256) {
        int v = h[i];
        if (v) atomicAdd(&bin_counts[i], v);
    }
}

__global__ void binscan_kernel(const int* __restrict__ bin_counts,
                               int* __restrict__ bin_off, int* __restrict__ bin_cur, int NB) {
    __shared__ int sh[MAXB];
    const int t = threadIdx.x;
    int v = (t < NB) ? bin_counts[t] : 0;
    sh[t] = v;
    __syncthreads();
    for (int s = 1; s < 256; s <<= 1) {
        int x = (t >= s) ? sh[t - s] : 0;
        __syncthreads();
        sh[t] += x;
        __syncthreads();
    }
    if (t < NB) {
        int ex = sh[t] - v;     // exclusive
        bin_off[t] = ex;
        bin_cur[t] = ex;
    }
}

// Block-level binning: tile-local LDS sort by bin, then bin-sorted write-out
// in contiguous runs. pairs[i] = (dlocal<<23) | src   (src < 2^23).
__device__ void stage_body(int blk, const int* __restrict__ src, const int* __restrict__ dst,
                           int* __restrict__ bin_cur, unsigned* __restrict__ pairs, int E) {
    __shared__ int sh_hist[MAXB];
    __shared__ int sh_off[MAXB];
    __shared__ int sh_ex[MAXB];
    __shared__ int sh_gbase[MAXB];
    __shared__ uint2 stg[TILE];
    const int t = threadIdx.x;
    const int base = blk * TILE;
    const int cnt = min(TILE, E - base);

    for (int i = t; i < MAXB; i += 256) sh_hist[i] = 0;
    __syncthreads();

    int s[16], d[16], r[16];
#pragma unroll
    for (int j = 0; j < 16; ++j) {
        const int k = j * 256 + t;
        if (k < cnt) {
            s[j] = src[base + k];
            d[j] = dst[base + k];
            r[j] = atomicAdd(&sh_hist[((unsigned)d[j]) >> SHIFT], 1);
        }
    }
    __syncthreads();

    const int hv = sh_hist[t];
    sh_off[t] = hv;
    __syncthreads();
    for (int st = 1; st < 256; st <<= 1) {
        int x = (t >= st) ? sh_off[t - st] : 0;
        __syncthreads();
        sh_off[t] += x;
        __syncthreads();
    }
    sh_ex[t] = sh_off[t] - hv;                      // exclusive within tile
    if (hv > 0) sh_gbase[t] = atomicAdd(&bin_cur[t], hv);
    __syncthreads();

#pragma unroll
    for (int j = 0; j < 16; ++j) {
        const int k = j * 256 + t;
        if (k < cnt) {
            int b = ((unsigned)d[j]) >> SHIFT;
            stg[sh_ex[b] + r[j]] = make_uint2((unsigned)s[j], (unsigned)d[j]);
        }
    }
    __syncthreads();

    for (int i = t; i < cnt; i += 256) {
        uint2 p = stg[i];
        int b = (int)(p.y >> SHIFT);
        unsigned w = ((p.y & (RANGE - 1)) << 23) | p.x;
        pairs[sh_gbase[b] + (i - sh_ex[b])] = w;
    }
}

// Per-bin: histogram pairs -> counts; intra-bin scan (+bin_off base) -> rowp;
// dinv from counts.
__global__ __launch_bounds__(256)
void binrowp_kernel(const unsigned* __restrict__ pairs, const int* __restrict__ bin_off,
                    float* __restrict__ dinv, int* __restrict__ rowp,
                    int N, int NB, int E) {
    __shared__ int c[RANGE];
    __shared__ int sh[256];
    const int b = blockIdx.x;
    const int t = threadIdx.x;
    const int nb = b << SHIFT;
    const int nr = min(RANGE, N - nb);
    for (int i = t; i < RANGE; i += 256) c[i] = 0;
    __syncthreads();
    const int lo = bin_off[b];
    const int hi = (b + 1 < NB) ? bin_off[b + 1] : E;
    for (int i = lo + t; i < hi; i += 256)
        atomicAdd(&c[pairs[i] >> 23], 1);
    __syncthreads();
    const int v0 = c[2 * t], v1 = c[2 * t + 1];
    const int pr = v0 + v1;
    sh[t] = pr;
    __syncthreads();
    for (int s = 1; s < 256; s <<= 1) {
        int x = (t >= s) ? sh[t - s] : 0;
        __syncthreads();
        sh[t] += x;
        __syncthreads();
    }
    const int ex = sh[t] - pr + lo;     // exclusive prefix + bin edge base
    if (2 * t < nr) {
        rowp[nb + 2 * t] = ex;
        dinv[nb + 2 * t] = rsqrtf((float)(v0 + 1));
    }
    if (2 * t + 1 < nr) {
        rowp[nb + 2 * t + 1] = ex + v0;
        dinv[nb + 2 * t + 1] = rsqrtf((float)(v1 + 1));
    }
    if (b == 0 && t == 0) rowp[N] = E;
}

// Per-bin fine scatter; emits packed (src<<15)|fixed15(dinv[src])
__global__ __launch_bounds__(256)
void fine_kernel(const unsigned* __restrict__ pairs, const int* __restrict__ bin_off,
                 const int* __restrict__ rowp, const float* __restrict__ dinv,
                 unsigned* __restrict__ colv1, int N, int NB, int E) {
    __shared__ int cur[RANGE];
    const int b = blockIdx.x;
    const int nb = b << SHIFT;
    const int nr = min(RANGE, N - nb);
    for (int i = threadIdx.x; i < nr; i += 256) cur[i] = rowp[nb + i];
    __syncthreads();
    const int lo = bin_off[b];
    const int hi = (b + 1 < NB) ? bin_off[b + 1] : E;
    for (int i = lo + threadIdx.x; i < hi; i += 256) {
        unsigned w = pairs[i];
        unsigned s = w & 0x7fffffu;
        int pos = atomicAdd(&cur[w >> 23], 1);
        unsigned w15 = __float2uint_rn(dinv[s] * 32767.0f);   // dinv in (0,1]
        colv1[pos] = (s << 15) | w15;
    }
}

// ------------------------------- GEMM body ---------------------------------
// Out[row][col] (bf16, N x 128) = A (N x K, bf16) @ W, via Wt[col][k] bf16.
// Barrier-free, LDS-free. Wave = 32 rows. A-loads in a DEPTH=4 register pipe
// (full unroll, K constexpr); MFMA waits only on this iteration's B while A
// refills stay outstanding.
template <int K>
__device__ void gemm_body(int blk, const unsigned short* __restrict__ A16,
                          const unsigned short* __restrict__ Wt,
                          unsigned short* __restrict__ Out, int nrows) {
    constexpr int NIT = K / 32;
    constexpr int DEPTH = (NIT < 4) ? NIT : 4;
    const int tid  = threadIdx.x;
    const int wave = tid >> 6;
    const int lane = tid & 63;
    const int q = lane >> 4;
    const int r = lane & 15;
    const int wrow = blk * 128 + wave * 32;
    const size_t row0 = (size_t)min(wrow + r,      nrows - 1);
    const size_t row1 = (size_t)min(wrow + 16 + r, nrows - 1);

    f32x4 acc[2][8];
#pragma unroll
    for (int s = 0; s < 2; ++s)
#pragma unroll
        for (int c = 0; c < 8; ++c) acc[s][c] = (f32x4){0.f, 0.f, 0.f, 0.f};

    bf16x8 preb[DEPTH][2];
#pragma unroll
    for (int i = 0; i < DEPTH; ++i) {
        const int kk = i * 32 + q * 8;
        preb[i][0] = *reinterpret_cast<const bf16x8*>(A16 + row0 * K + kk);
        preb[i][1] = *reinterpret_cast<const bf16x8*>(A16 + row1 * K + kk);
    }

#pragma unroll
    for (int it = 0; it < NIT; ++it) {
        const int slot = it % DEPTH;
        const int kk = it * 32 + q * 8;

        bf16x8 bfr[8];
#pragma unroll
        for (int c = 0; c < 8; ++c)
            bfr[c] = *reinterpret_cast<const bf16x8*>(Wt + (size_t)(c * 16 + r) * K + kk);

        const bf16x8 a0 = preb[slot][0];
        const bf16x8 a1 = preb[slot][1];

        if (it + DEPTH < NIT) {
            const int kk2 = (it + DEPTH) * 32 + q * 8;
            preb[slot][0] = *reinterpret_cast<const bf16x8*>(A16 + row0 * K + kk2);
            preb[slot][1] = *reinterpret_cast<const bf16x8*>(A16 + row1 * K + kk2);
        }

#pragma unroll
        for (int c = 0; c < 8; ++c) {
            acc[0][c] = __builtin_amdgcn_mfma_f32_16x16x32_bf16(a0, bfr[c], acc[0][c], 0, 0, 0);
            acc[1][c] = __builtin_amdgcn_mfma_f32_16x16x32_bf16(a1, bfr[c], acc[1][c], 0, 0, 0);
        }
    }

#pragma unroll
    for (int s = 0; s < 2; ++s)
#pragma unroll
        for (int v = 0; v < 4; ++v) {
            const int row = wrow + s * 16 + q * 4 + v;
            if (row < nrows) {
#pragma unroll
                for (int c = 0; c < 8; ++c)
                    Out[(size_t)row * 128 + c * 16 + r] = f2bf(acc[s][c][v]);
            }
        }
}

// ---------------------- D1: convert | wt1 | wt2 | bincount -----------------

__global__ __launch_bounds__(256)
void d1_kernel(const float* __restrict__ x, unsigned short* __restrict__ xbf,
               long long NK,
               const float* __restrict__ W1, const float* __restrict__ W2,
               unsigned short* __restrict__ wt1, unsigned short* __restrict__ wt2,
               int K1, const int* __restrict__ dst, int* __restrict__ bin_counts,
               int E, int NB, int ncb, int nb1, int nb2) {
    const int b = blockIdx.x;
    const int tid = threadIdx.x;
    if (b < ncb) {                                   // x fp32 -> bf16 (stream)
        const long long base = ((long long)b * 256 + tid) * 8;
        if (base + 8 <= NK) {
            const float4 x0 = *reinterpret_cast<const float4*>(x + base);
            const float4 x1 = *reinterpret_cast<const float4*>(x + base + 4);
            uint4 o;
            o.x = packbf(x0.x, x0.y); o.y = packbf(x0.z, x0.w);
            o.z = packbf(x1.x, x1.y); o.w = packbf(x1.z, x1.w);
            *reinterpret_cast<uint4*>(xbf + base) = o;
        } else {
            for (long long i = base; i < NK; ++i) xbf[i] = f2bf(x[i]);
        }
    } else if (b < ncb + nb1) {                      // W1 -> wt1[n][k] bf16
        int idx = (b - ncb) * 256 + tid;
        if (idx < 128 * K1) {
            int nn = idx / K1, k = idx - nn * K1;
            wt1[(size_t)nn * K1 + k] = f2bf(W1[(size_t)k * 128 + nn]);
        }
    } else if (b < ncb + nb1 + nb2) {                // W2 -> wt2[n][k] bf16
        int idx = (b - ncb - nb1) * 256 + tid;
        if (idx < 128 * 128) {
            int nn = idx >> 7, k = idx & 127;
            wt2[(size_t)nn * 128 + k] = f2bf(W2[(size_t)k * 128 + nn]);
        }
    } else {                                         // coarse bin histogram
        bincount_body(b - ncb - nb1 - nb2, dst, bin_counts, E, NB);
    }
}

// ---------------------- D3: stage | gemm1 co-launch ------------------------

__global__ __launch_bounds__(256)
void d3_kernel(const int* __restrict__ src, const int* __restrict__ dst,
               int* __restrict__ bin_cur, unsigned* __restrict__ pairs, int E,
               int ntiles, const unsigned short* __restrict__ xbf,
               const unsigned short* __restrict__ wt1,
               unsigned short* __restrict__ xw, int nrows) {
    if ((int)blockIdx.x < ntiles)
        stage_body(blockIdx.x, src, dst, bin_cur, pairs, E);
    else
        gemm_body<256>(blockIdx.x - ntiles, xbf, wt1, xw, nrows);
}

__global__ __launch_bounds__(256)
void gemm2_kernel(const unsigned short* __restrict__ A,
                  const unsigned short* __restrict__ Wt,
                  unsigned short* __restrict__ Out, int nrows) {
    gemm_body<128>(blockIdx.x, A, Wt, Out, nrows);
}

// --------------------------- Aggregation -----------------------------------
// One wave per node. Lane c=lane&15 owns features 8c..8c+7 (uint4 = 8 bf16);
// four 16-lane quarters process edges t..t+3 concurrently (dwordx4 gather =
// 1KB/wave-instr). colv entry packed (st<<15)|w15 -> ONE shuffle per group.
// f32x2 accumulators target v_pk_fma_f32. Merge via shfl_xor(16,32).

#define AGG_EDGE_LOOP(XW)                                                      \
    for (int base = beg; base < end; base += 64) {                             \
        const int e = base + lane;                                             \
        const unsigned cw = (e < end) ? colv1[e] : 0u;                         \
        const int cnt = min(64, end - base);                                   \
        _Pragma("unroll 4")                                                    \
        for (int t = 0; t < cnt; t += 4) {                                     \
            const unsigned cg = (unsigned)__shfl((int)cw, t + q4);             \
            const unsigned st = cg >> 15;                                      \
            const float    wt = (float)(cg & 0x7fffu) * (1.0f / 32767.0f);     \
            const uint4 uu = *reinterpret_cast<const uint4*>(                  \
                (const char*)(XW) + ((st << 8) + coff));                       \
            A0 += (f32x2){bflo(uu.x), bfhi(uu.x)} * wt;                        \
            A1 += (f32x2){bflo(uu.y), bfhi(uu.y)} * wt;                        \
            A2 += (f32x2){bflo(uu.z), bfhi(uu.z)} * wt;                        \
            A3 += (f32x2){bflo(uu.w), bfhi(uu.w)} * wt;                        \
        }                                                                      \
    }                                                                          \
    A0 += __shfl_xor(A0, 16); A1 += __shfl_xor(A1, 16);                        \
    A2 += __shfl_xor(A2, 16); A3 += __shfl_xor(A3, 16);                        \
    A0 += __shfl_xor(A0, 32); A1 += __shfl_xor(A1, 32);                        \
    A2 += __shfl_xor(A2, 32); A3 += __shfl_xor(A3, 32);

__device__ __forceinline__ f32x2 __shfl_xor(f32x2 v, int m) {
    return (f32x2){__shfl_xor(v[0], m), __shfl_xor(v[1], m)};
}

__global__ __launch_bounds__(256)
void agg1_kernel(const unsigned short* __restrict__ xw, const unsigned* __restrict__ colv1,
                 const int* __restrict__ rowp, const float* __restrict__ dinv,
                 const float* __restrict__ b1, const float* __restrict__ Wc,
                 const float* __restrict__ bc, uint4* __restrict__ h1,
                 float* __restrict__ outp, int n) {
    const int node = blockIdx.x * 4 + (threadIdx.x >> 6);
    if (node >= n) return;
    const int lane = threadIdx.x & 63;
    const int c    = lane & 15;
    const int q4   = lane >> 4;
    const unsigned coff = (unsigned)c << 4;
    const float di = dinv[node];

    f32x2 A0 = {0.f,0.f}, A1 = {0.f,0.f}, A2 = {0.f,0.f}, A3 = {0.f,0.f};
    {   // self-loop (quarter 0 only; merged by xor reductions)
        const float ws = (q4 == 0) ? di : 0.f;
        const uint4 uu = *reinterpret_cast<const uint4*>(
            (const char*)xw + (((unsigned)node << 8) + coff));
        A0 += (f32x2){bflo(uu.x), bfhi(uu.x)} * ws;
        A1 += (f32x2){bflo(uu.y), bfhi(uu.y)} * ws;
        A2 += (f32x2){bflo(uu.z), bfhi(uu.z)} * ws;
        A3 += (f32x2){bflo(uu.w), bfhi(uu.w)} * ws;
    }

    const int beg = rowp[node], end = rowp[node + 1];
    AGG_EDGE_LOOP(xw)

    const float4 bb0 = reinterpret_cast<const float4*>(b1)[2*c];
    const float4 bb1 = reinterpret_cast<const float4*>(b1)[2*c + 1];
    float a0 = fmaxf(A0[0]*di + bb0.x, 0.f), a1 = fmaxf(A0[1]*di + bb0.y, 0.f);
    float a2 = fmaxf(A1[0]*di + bb0.z, 0.f), a3 = fmaxf(A1[1]*di + bb0.w, 0.f);
    float a4 = fmaxf(A2[0]*di + bb1.x, 0.f), a5 = fmaxf(A2[1]*di + bb1.y, 0.f);
    float a6 = fmaxf(A3[0]*di + bb1.z, 0.f), a7 = fmaxf(A3[1]*di + bb1.w, 0.f);

    if (q4 == 0)
        h1[((unsigned)node << 4) + c] =
            make_uint4(packbf(a0,a1), packbf(a2,a3), packbf(a4,a5), packbf(a6,a7));

    const float4 w0 = reinterpret_cast<const float4*>(Wc)[4*c];
    const float4 w1 = reinterpret_cast<const float4*>(Wc)[4*c + 1];
    const float4 w2 = reinterpret_cast<const float4*>(Wc)[4*c + 2];
    const float4 w3 = reinterpret_cast<const float4*>(Wc)[4*c + 3];
    float c0 = a0*w0.x + a1*w0.z + a2*w1.x + a3*w1.z
             + a4*w2.x + a5*w2.z + a6*w3.x + a7*w3.z;
    float c1 = a0*w0.y + a1*w0.w + a2*w1.y + a3*w1.w
             + a4*w2.y + a5*w2.w + a6*w3.y + a7*w3.w;
    if (q4) { c0 = 0.f; c1 = 0.f; }   // quarters hold duplicates post-merge
#pragma unroll
    for (int off = 32; off; off >>= 1) {
        c0 += __shfl_down(c0, off);
        c1 += __shfl_down(c1, off);
    }
    if (lane == 0) {
        outp[2 * (size_t)node]     = 0.5f * (c0 + bc[0]);
        outp[2 * (size_t)node + 1] = 0.5f * (c1 + bc[1]);
    }
}

__global__ __launch_bounds__(256)
void agg2_kernel(const unsigned short* __restrict__ xw2, const uint4* __restrict__ h1,
                 const unsigned* __restrict__ colv1, const int* __restrict__ rowp,
                 const float* __restrict__ dinv, const float* __restrict__ b2,
                 const float* __restrict__ Wf, const float* __restrict__ bfv,
                 const float* __restrict__ hnode, float* __restrict__ outp, int n) {
    const int node = blockIdx.x * 4 + (threadIdx.x >> 6);
    if (node >= n) return;
    const int lane = threadIdx.x & 63;
    const int c    = lane & 15;
    const int q4   = lane >> 4;
    const unsigned coff = (unsigned)c << 4;
    const float di = dinv[node];

    f32x2 A0 = {0.f,0.f}, A1 = {0.f,0.f}, A2 = {0.f,0.f}, A3 = {0.f,0.f};
    {
        const float ws = (q4 == 0) ? di : 0.f;
        const uint4 uu = *reinterpret_cast<const uint4*>(
            (const char*)xw2 + (((unsigned)node << 8) + coff));
        A0 += (f32x2){bflo(uu.x), bfhi(uu.x)} * ws;
        A1 += (f32x2){bflo(uu.y), bfhi(uu.y)} * ws;
        A2 += (f32x2){bflo(uu.z), bfhi(uu.z)} * ws;
        A3 += (f32x2){bflo(uu.w), bfhi(uu.w)} * ws;
    }

    const int beg = rowp[node], end = rowp[node + 1];
    AGG_EDGE_LOOP(xw2)

    const float4 bb0 = reinterpret_cast<const float4*>(b2)[2*c];
    const float4 bb1 = reinterpret_cast<const float4*>(b2)[2*c + 1];
    float h20 = fmaxf(A0[0]*di + bb0.x, 0.f), h21 = fmaxf(A0[1]*di + bb0.y, 0.f);
    float h22 = fmaxf(A1[0]*di + bb0.z, 0.f), h23 = fmaxf(A1[1]*di + bb0.w, 0.f);
    float h24 = fmaxf(A2[0]*di + bb1.x, 0.f), h25 = fmaxf(A2[1]*di + bb1.y, 0.f);
    float h26 = fmaxf(A3[0]*di + bb1.z, 0.f), h27 = fmaxf(A3[1]*di + bb1.w, 0.f);

    const float alpha = hnode[node];
    const float beta  = 1.f - alpha;
    const uint4 hh = h1[((unsigned)node << 4) + c];
    const float ha0 = alpha*h20 + beta*bflo(hh.x);
    const float ha1 = alpha*h21 + beta*bfhi(hh.x);
    const float ha2 = alpha*h22 + beta*bflo(hh.y);
    const float ha3 = alpha*h23 + beta*bfhi(hh.y);
    const float ha4 = alpha*h24 + beta*bflo(hh.z);
    const float ha5 = alpha*h25 + beta*bfhi(hh.z);
    const float ha6 = alpha*h26 + beta*bflo(hh.w);
    const float ha7 = alpha*h27 + beta*bfhi(hh.w);

    const float4 w0 = reinterpret_cast<const float4*>(Wf)[4*c];
    const float4 w1 = reinterpret_cast<const float4*>(Wf)[4*c + 1];
    const float4 w2 = reinterpret_cast<const float4*>(Wf)[4*c + 2];
    const float4 w3 = reinterpret_cast<const float4*>(Wf)[4*c + 3];
    float f0 = ha0*w0.x + ha1*w0.z + ha2*w1.x + ha3*w1.z
             + ha4*w2.x + ha5*w2.z + ha6*w3.x + ha7*w3.z;
    float f1 = ha0*w0.y + ha1*w0.w + ha2*w1.y + ha3*w1.w
             + ha4*w2.y + ha5*w2.w + ha6*w3.y + ha7*w3.w;
    if (q4) { f0 = 0.f; f1 = 0.f; }
#pragma unroll
    for (int off = 32; off; off >>= 1) {
        f0 += __shfl_down(f0, off);
        f1 += __shfl_down(f1, off);
    }
    if (lane == 0) {
        outp[2 * (size_t)node]     += 0.5f * (f0 + bfv[0]);
        outp[2 * (size_t)node + 1] += 0.5f * (f1 + bfv[1]);
    }
}

// ------------------------------ launch -------------------------------------

extern "C" void kernel_launch(void* const* d_in, const int* in_sizes, int n_in,
                              void* d_out, int out_size, void* d_ws, size_t ws_size,
                              hipStream_t stream) {
    const float* x     = (const float*)d_in[0];
    const int*   ei    = (const int*)d_in[1];     // int32 per harness contract
    const float* hnode = (const float*)d_in[2];
    const float* W1    = (const float*)d_in[3];
    const float* b1    = (const float*)d_in[4];
    const float* W2    = (const float*)d_in[5];
    const float* b2    = (const float*)d_in[6];
    const float* Wc    = (const float*)d_in[7];
    const float* bc    = (const float*)d_in[8];
    const float* Wf    = (const float*)d_in[9];
    const float* bfv   = (const float*)d_in[10];

    const int N  = in_sizes[2];
    const int E  = in_sizes[1] / 2;
    const int K1 = in_sizes[3] / HID;   // 256 (fixed by problem shape)
    const int NB = (N + RANGE - 1) >> SHIFT;
    const int* srcv = ei;
    const int* dstv = ei + E;
    float* outp = (float*)d_out;

    char* ws = (char*)d_ws;
    size_t off = 0;
    auto alloc = [&](size_t bytes) -> char* {
        char* p = ws + off;
        off += (bytes + 255) & ~(size_t)255;
        return p;
    };
    unsigned short* xbf      = (unsigned short*)alloc((size_t)N * K1 * 2);   // 51.2 MB
    unsigned short* xw       = (unsigned short*)alloc((size_t)N * HID * 2);  // 25.6 MB
    unsigned short* h1       = (unsigned short*)alloc((size_t)N * HID * 2);  // 25.6 MB
    float*          dinv     = (float*)alloc((size_t)N * 4);
    int*            rowp     = (int*)alloc((size_t)(N + 1) * 4);
    unsigned*       colv1    = (unsigned*)alloc((size_t)E * 4);              // 6.4 MB
    unsigned*       pairs    = (unsigned*)alloc((size_t)E * 4);              // 6.4 MB
    int*            bin_counts = (int*)alloc(MAXB * 4);
    int*            bin_off    = (int*)alloc(MAXB * 4);
    int*            bin_cur    = (int*)alloc(MAXB * 4);
    unsigned short* wt1      = (unsigned short*)alloc((size_t)HID * K1 * 2);
    unsigned short* wt2      = (unsigned short*)alloc((size_t)HID * HID * 2);

    const long long NK = (long long)N * K1;
    const int ncb = (int)((NK + 2047) / 2048);          // convert blocks
    const int nb1 = (128 * K1 + 255) / 256;             // wt1 blocks
    const int nb2 = (128 * 128 + 255) / 256;            // wt2 blocks
    const int ntiles = (E + TILE - 1) / TILE;
    const int ngemm  = (N + 127) / 128;

    hipMemsetAsync(bin_counts, 0, MAXB * 4, stream);

    d1_kernel<<<ncb + nb1 + nb2 + ntiles, 256, 0, stream>>>(
        x, xbf, NK, W1, W2, wt1, wt2, K1, dstv, bin_counts, E, NB, ncb, nb1, nb2);

    binscan_kernel<<<1, 256, 0, stream>>>(bin_counts, bin_off, bin_cur, NB);

    d3_kernel<<<ntiles + ngemm, 256, 0, stream>>>(
        srcv, dstv, bin_cur, pairs, E, ntiles, xbf, wt1, xw, N);

    binrowp_kernel<<<NB, 256, 0, stream>>>(pairs, bin_off, dinv, rowp, N, NB, E);
    fine_kernel<<<NB, 256, 0, stream>>>(pairs, bin_off, rowp, dinv, colv1, N, NB, E);

    agg1_kernel<<<(N + 3) / 4, 256, 0, stream>>>(xw, colv1, rowp, dinv,
                                                 b1, Wc, bc, (uint4*)h1, outp, N);
    gemm2_kernel<<<ngemm, 256, 0, stream>>>(h1, wt2, xw, N);
    agg2_kernel<<<(N + 3) / 4, 256, 0, stream>>>(xw, (const uint4*)h1, colv1,
                                                 rowp, dinv, b2, Wf, bfv, hnode, outp, N);
}